// Round 3
// baseline (250.748 us; speedup 1.0000x reference)
//
#include <hip/hip_runtime.h>

// Problem constants (B=16, T=512, N=2048, U=64) — all inputs/outputs FP32.
#define N_DIM 2048
#define U_DIM 64
#define M_DIM 8192   // B*T
#define K_DIM 2048   // = N

typedef __bf16 bf16x8 __attribute__((ext_vector_type(8)));
typedef float  floatx4  __attribute__((ext_vector_type(4)));
typedef float  floatx16 __attribute__((ext_vector_type(16)));
typedef unsigned short ushort8 __attribute__((ext_vector_type(8)));

#define AS1 __attribute__((address_space(1)))
#define AS3 __attribute__((address_space(3)))

__device__ __forceinline__ unsigned short f_to_bf16_rne(float f) {
    unsigned int x;
    __builtin_memcpy(&x, &f, 4);
    x += 0x7fffu + ((x >> 16) & 1u);
    return (unsigned short)(x >> 16);
}

// ---------------------------------------------------------------------------
// Kernel 1: wbar[k] = mean_i W[i,k]  (fp32), bmean = mean(b)
// ---------------------------------------------------------------------------
__global__ __launch_bounds__(256) void prep_kernel(
    const float* __restrict__ W, const float* __restrict__ b,
    float* __restrict__ wbar, float* __restrict__ bmean) {
    int k = blockIdx.x * 256 + threadIdx.x;
    float s = 0.f;
#pragma unroll
    for (int i = 0; i < U_DIM; ++i) s += W[i * N_DIM + k];
    wbar[k] = s * (1.f / U_DIM);

    if (blockIdx.x == 0 && threadIdx.x < 64) {
        float v = b[threadIdx.x];
#pragma unroll
        for (int off = 32; off > 0; off >>= 1) v += __shfl_down(v, off);
        if (threadIdx.x == 0) bmean[0] = v * (1.f / U_DIM);
    }
}

// ---------------------------------------------------------------------------
// Kernel 2: weff[j,k] = bf16( Adj[j,k] * wbar[k] )
// ---------------------------------------------------------------------------
__global__ __launch_bounds__(256) void weff_kernel(
    const float* __restrict__ Adj, const float* __restrict__ wbar,
    unsigned short* __restrict__ weff) {
    long long idx = ((long long)blockIdx.x * 256 + threadIdx.x) * 8;
    int k = (int)(idx & (N_DIM - 1));
    floatx4 a0 = *(const floatx4*)(Adj + idx);
    floatx4 a1 = *(const floatx4*)(Adj + idx + 4);
    floatx4 w0 = *(const floatx4*)(wbar + k);
    floatx4 w1 = *(const floatx4*)(wbar + k + 4);
    ushort8 ov;
#pragma unroll
    for (int j = 0; j < 4; ++j) {
        ov[j]     = f_to_bf16_rne(a0[j] * w0[j]);
        ov[j + 4] = f_to_bf16_rne(a1[j] * w1[j]);
    }
    *(ushort8*)(weff + idx) = ov;
}

// ---------------------------------------------------------------------------
// Kernel 3: x (fp32) -> bf16 bits, 8 elems/thread.
// ---------------------------------------------------------------------------
__global__ __launch_bounds__(256) void convx_kernel(
    const float* __restrict__ x, unsigned short* __restrict__ xbf) {
    long long idx = ((long long)blockIdx.x * 256 + threadIdx.x) * 8;
    floatx4 a0 = *(const floatx4*)(x + idx);
    floatx4 a1 = *(const floatx4*)(x + idx + 4);
    ushort8 ov;
#pragma unroll
    for (int j = 0; j < 4; ++j) {
        ov[j]     = f_to_bf16_rne(a0[j]);
        ov[j + 4] = f_to_bf16_rne(a1[j]);
    }
    *(ushort8*)(xbf + idx) = ov;
}

// ---------------------------------------------------------------------------
// Kernel 4: C[m,j] = sum_k A[m,k]*Bt[j,k] + bmean   (bf16 in, fp32 acc/out)
// 128x128 tile, BK=32, 4 waves; wave = 64x64 via 2x2 of mfma_f32_32x32x16.
// LDS tile layout XOR-swizzled: element (row, kc-chunk of 8) lives at
//   row*32 + (kc ^ ((row>>1)&3))*8   (elements)
// -> ds_read_b128 fragment reads are exactly 2-way per quarter-wave (free,
//    m136), vs 8-way (2.94x) for the naive row-major layout (8.4M conflicts
//    in R2's profile). Staging stays global_load_lds-legal: lane l fetches
//    the permuted chunk so LDS dest remains base + l*16.
// ---------------------------------------------------------------------------
#define BM 128
#define BN 128
#define BK 32

__global__ __launch_bounds__(256) void gemm_bt_kernel(
    const unsigned short* __restrict__ A,    // [M, K] bf16 bits (xbf)
    const unsigned short* __restrict__ Bt,   // [N, K] bf16 bits (weff)
    const float* __restrict__ bmeanp,
    float* __restrict__ C) {                 // [M, N] fp32
    __shared__ __align__(16) unsigned short sA[BM * BK];
    __shared__ __align__(16) unsigned short sB[BN * BK];

    const int tid  = threadIdx.x;
    const int w    = tid >> 6;    // wave 0..3
    const int lane = tid & 63;
    const int tile_m = blockIdx.y * BM;
    const int tile_n = blockIdx.x * BN;

    const float bmean = bmeanp[0];

    // --- staging: wave w stages chunks (w*2), (w*2+1) of A and B.
    // Chunk c = rows c*16..c*16+15. Lane l: row = l>>2, fetched k-chunk is
    // swizzled: kc = (l&3) ^ ((l>>3)&3)  (= (l&3) ^ ((row>>1)&3)).
    const int srow = lane >> 2;
    const int skc  = (lane & 3) ^ ((lane >> 3) & 3);
    const int scol = skc * 8;
    const unsigned short* gA0 = A + (size_t)(tile_m + (w * 2 + 0) * 16 + srow) * K_DIM + scol;
    const unsigned short* gA1 = A + (size_t)(tile_m + (w * 2 + 1) * 16 + srow) * K_DIM + scol;
    const unsigned short* gB0 = Bt + (size_t)(tile_n + (w * 2 + 0) * 16 + srow) * K_DIM + scol;
    const unsigned short* gB1 = Bt + (size_t)(tile_n + (w * 2 + 1) * 16 + srow) * K_DIM + scol;
    unsigned short* lA0 = &sA[(w * 2 + 0) * 16 * BK];
    unsigned short* lA1 = &sA[(w * 2 + 1) * 16 * BK];
    unsigned short* lB0 = &sB[(w * 2 + 0) * 16 * BK];
    unsigned short* lB1 = &sB[(w * 2 + 1) * 16 * BK];

    // --- fragment read offsets. 32x32x16 A/B frag: m(or n) = lane&31,
    // k = (lane>>5)*8 + j. Per BK=32 iter: ksteps s=0,1 -> kc = (lane>>5)+2s.
    const int wrow = (w >> 1) * 64;
    const int wcol = (w & 1) * 64;
    const int fr = lane & 31;
    const int fh = lane >> 5;          // 0..1
    int aoff[2][2], boff[2][2];        // [ti][s]
#pragma unroll
    for (int ti = 0; ti < 2; ++ti) {
#pragma unroll
        for (int s = 0; s < 2; ++s) {
            int ra = wrow + ti * 32 + fr;
            int rb = wcol + ti * 32 + fr;
            int kc = fh + 2 * s;
            aoff[ti][s] = ra * BK + ((kc ^ ((ra >> 1) & 3)) * 8);
            boff[ti][s] = rb * BK + ((kc ^ ((rb >> 1) & 3)) * 8);
        }
    }

    floatx16 acc[2][2];
#pragma unroll
    for (int tm = 0; tm < 2; ++tm)
#pragma unroll
        for (int tn = 0; tn < 2; ++tn)
#pragma unroll
            for (int r = 0; r < 16; ++r) acc[tm][tn][r] = 0.f;

    for (int k0 = 0; k0 < K_DIM; k0 += BK) {
        __syncthreads();  // prev iteration's LDS reads done before overwrite
        __builtin_amdgcn_global_load_lds((const AS1 void*)(gA0 + k0), (AS3 void*)lA0, 16, 0, 0);
        __builtin_amdgcn_global_load_lds((const AS1 void*)(gA1 + k0), (AS3 void*)lA1, 16, 0, 0);
        __builtin_amdgcn_global_load_lds((const AS1 void*)(gB0 + k0), (AS3 void*)lB0, 16, 0, 0);
        __builtin_amdgcn_global_load_lds((const AS1 void*)(gB1 + k0), (AS3 void*)lB1, 16, 0, 0);
        __syncthreads();  // vmcnt drained before barrier

        bf16x8 af[2][2], bf[2][2];
#pragma unroll
        for (int ti = 0; ti < 2; ++ti)
#pragma unroll
            for (int s = 0; s < 2; ++s) {
                af[ti][s] = *(const bf16x8*)&sA[aoff[ti][s]];
                bf[ti][s] = *(const bf16x8*)&sB[boff[ti][s]];
            }
#pragma unroll
        for (int s = 0; s < 2; ++s)
#pragma unroll
            for (int tm = 0; tm < 2; ++tm)
#pragma unroll
                for (int tn = 0; tn < 2; ++tn)
                    acc[tm][tn] = __builtin_amdgcn_mfma_f32_32x32x16_bf16(
                        af[tm][s], bf[tn][s], acc[tm][tn], 0, 0, 0);
    }

    // Epilogue. 32x32 C/D: col = lane&31, row = (reg&3)+8*(reg>>2)+4*(lane>>5)
    // [m74/m101 verified]
#pragma unroll
    for (int tm = 0; tm < 2; ++tm)
#pragma unroll
        for (int tn = 0; tn < 2; ++tn)
#pragma unroll
            for (int r = 0; r < 16; ++r) {
                int row = (r & 3) + 8 * (r >> 2) + 4 * fh;
                int gm = tile_m + wrow + tm * 32 + row;
                int gn = tile_n + wcol + tn * 32 + fr;
                C[(size_t)gm * N_DIM + gn] = acc[tm][tn][r] + bmean;
            }
}

// ---------------------------------------------------------------------------
extern "C" void kernel_launch(void* const* d_in, const int* in_sizes, int n_in,
                              void* d_out, int out_size, void* d_ws, size_t ws_size,
                              hipStream_t stream) {
    (void)in_sizes; (void)n_in; (void)out_size;
    const float* x   = (const float*)d_in[0];  // [16,512,2048]
    const float* Adj = (const float*)d_in[1];  // [2048,2048]
    const float* W   = (const float*)d_in[2];  // [64,2048]
    const float* b   = (const float*)d_in[3];  // [64]
    float* out = (float*)d_out;                // [16,512,2048] fp32

    // ws: wbar @0 (8 KB) | bmean @8192 | weff bf16 @16384 (8.39 MB) | xbf
    char* ws = (char*)d_ws;
    float* wbar  = (float*)ws;
    float* bmean = (float*)(ws + 8192);
    unsigned short* weff = (unsigned short*)(ws + 16384);
    const size_t weff_bytes = (size_t)N_DIM * N_DIM * 2;
    const size_t xbf_off = 16384 + weff_bytes;
    unsigned short* xbf = (unsigned short*)(ws + xbf_off);

    size_t avail = (ws_size > xbf_off) ? (ws_size - xbf_off) : 0;
    long long max_rows = (long long)(avail / ((size_t)K_DIM * 2)) / BM * BM;
    if (max_rows < BM) max_rows = BM;
    if (max_rows > M_DIM) max_rows = M_DIM;

    prep_kernel<<<N_DIM / 256, 256, 0, stream>>>(W, b, wbar, bmean);
    weff_kernel<<<(int)(((size_t)N_DIM * N_DIM / 8) / 256), 256, 0, stream>>>(Adj, wbar, weff);

    for (long long m0 = 0; m0 < M_DIM; m0 += max_rows) {
        long long rows = (M_DIM - m0 < max_rows) ? (M_DIM - m0) : max_rows;
        convx_kernel<<<(int)rows, 256, 0, stream>>>(x + m0 * K_DIM, xbf);
        dim3 grid(N_DIM / BN, (int)(rows / BM));
        gemm_bt_kernel<<<grid, 256, 0, stream>>>(xbf, weff, bmean, out + m0 * (size_t)N_DIM);
    }
}

// Round 4
// 226.679 us; speedup vs baseline: 1.1062x; 1.1062x over previous
//
#include <hip/hip_runtime.h>

// Problem constants (B=16, T=512, N=2048, U=64) — all inputs/outputs FP32.
#define N_DIM 2048
#define U_DIM 64
#define M_DIM 8192   // B*T
#define K_DIM 2048   // = N

typedef __bf16 bf16x8 __attribute__((ext_vector_type(8)));
typedef float  floatx4 __attribute__((ext_vector_type(4)));
typedef unsigned short ushort8 __attribute__((ext_vector_type(8)));

#define AS1 __attribute__((address_space(1)))
#define AS3 __attribute__((address_space(3)))

__device__ __forceinline__ unsigned short f_to_bf16_rne(float f) {
    unsigned int x;
    __builtin_memcpy(&x, &f, 4);
    x += 0x7fffu + ((x >> 16) & 1u);
    return (unsigned short)(x >> 16);
}

// ---------------------------------------------------------------------------
// Kernel 1: wbar[k] = mean_i W[i,k]  (fp32), bmean = mean(b)
// ---------------------------------------------------------------------------
__global__ __launch_bounds__(256) void prep_kernel(
    const float* __restrict__ W, const float* __restrict__ b,
    float* __restrict__ wbar, float* __restrict__ bmean) {
    int k = blockIdx.x * 256 + threadIdx.x;
    float s = 0.f;
#pragma unroll
    for (int i = 0; i < U_DIM; ++i) s += W[i * N_DIM + k];
    wbar[k] = s * (1.f / U_DIM);

    if (blockIdx.x == 0 && threadIdx.x < 64) {
        float v = b[threadIdx.x];
#pragma unroll
        for (int off = 32; off > 0; off >>= 1) v += __shfl_down(v, off);
        if (threadIdx.x == 0) bmean[0] = v * (1.f / U_DIM);
    }
}

// ---------------------------------------------------------------------------
// Kernel 2: weff[j,k] = bf16( Adj[j,k] * wbar[k] )
// ---------------------------------------------------------------------------
__global__ __launch_bounds__(256) void weff_kernel(
    const float* __restrict__ Adj, const float* __restrict__ wbar,
    unsigned short* __restrict__ weff) {
    long long idx = ((long long)blockIdx.x * 256 + threadIdx.x) * 8;
    int k = (int)(idx & (N_DIM - 1));
    floatx4 a0 = *(const floatx4*)(Adj + idx);
    floatx4 a1 = *(const floatx4*)(Adj + idx + 4);
    floatx4 w0 = *(const floatx4*)(wbar + k);
    floatx4 w1 = *(const floatx4*)(wbar + k + 4);
    ushort8 ov;
#pragma unroll
    for (int j = 0; j < 4; ++j) {
        ov[j]     = f_to_bf16_rne(a0[j] * w0[j]);
        ov[j + 4] = f_to_bf16_rne(a1[j] * w1[j]);
    }
    *(ushort8*)(weff + idx) = ov;
}

// ---------------------------------------------------------------------------
// Kernel 3: x (fp32) -> bf16 bits, 8 elems/thread.
// ---------------------------------------------------------------------------
__global__ __launch_bounds__(256) void convx_kernel(
    const float* __restrict__ x, unsigned short* __restrict__ xbf) {
    long long idx = ((long long)blockIdx.x * 256 + threadIdx.x) * 8;
    floatx4 a0 = *(const floatx4*)(x + idx);
    floatx4 a1 = *(const floatx4*)(x + idx + 4);
    ushort8 ov;
#pragma unroll
    for (int j = 0; j < 4; ++j) {
        ov[j]     = f_to_bf16_rne(a0[j]);
        ov[j + 4] = f_to_bf16_rne(a1[j]);
    }
    *(ushort8*)(xbf + idx) = ov;
}

// ---------------------------------------------------------------------------
// Kernel 4: C[m,j] = sum_k A[m,k]*Bt[j,k] + bmean   (bf16 in, fp32 acc/out)
// 128x128 tile, BK=64 (32 K-iters, half the barrier drains of BK=32),
// 4 waves; wave = 64x64 via 4x4 of mfma_f32_16x16x32, 2 k-steps per iter.
// LDS rows are 128 B (full bank wrap) -> XOR swizzle: 16 B chunk kc of row r
// lives at slot kc ^ (r&7). Fragment quarter-wave reads hit 8 distinct bank
// groups (2-way = free, m136). Staging stays global_load_lds-legal: lane l
// of chunk c fetches global kchunk (l&7)^(l>>3) for row c*8+(l>>3); LDS dest
// remains base + l*16.
// ---------------------------------------------------------------------------
#define BM 128
#define BN 128
#define BK 64

__global__ __launch_bounds__(256) void gemm_bt_kernel(
    const unsigned short* __restrict__ A,    // [M, K] bf16 bits (xbf)
    const unsigned short* __restrict__ Bt,   // [N, K] bf16 bits (weff)
    const float* __restrict__ bmeanp,
    float* __restrict__ C) {                 // [M, N] fp32
    __shared__ __align__(16) unsigned short sA[BM * BK];  // 16 KB
    __shared__ __align__(16) unsigned short sB[BN * BK];  // 16 KB

    const int tid  = threadIdx.x;
    const int w    = tid >> 6;    // wave 0..3
    const int lane = tid & 63;
    const int tile_m = blockIdx.y * BM;
    const int tile_n = blockIdx.x * BN;

    const float bmean = bmeanp[0];

    // --- staging: chunk = 1024 B = 8 rows of 128 B. 16 chunks each for A,B;
    // wave w stages A chunks w*4..w*4+3 and B chunks w*4..w*4+3.
    const int srow_in = lane >> 3;                    // 0..7 row within chunk
    const int skc     = (lane & 7) ^ srow_in;         // swizzled fetch chunk
    const int scol    = skc * 8;                      // element col
    const unsigned short* gA[4];
    const unsigned short* gB[4];
    unsigned short* lA[4];
    unsigned short* lB[4];
#pragma unroll
    for (int i = 0; i < 4; ++i) {
        int c = w * 4 + i;
        gA[i] = A  + (size_t)(tile_m + c * 8 + srow_in) * K_DIM + scol;
        gB[i] = Bt + (size_t)(tile_n + c * 8 + srow_in) * K_DIM + scol;
        lA[i] = &sA[c * 8 * BK];
        lB[i] = &sB[c * 8 * BK];
    }

    // --- fragment read offsets. 16x16x32 frag: m(n)=lane&15, k=(lane>>4)*8+j.
    // K-step s in {0,1}: kc = s*4 + fq; slot = kc ^ (row&7) = kc ^ (fr&7).
    const int wrow = (w >> 1) * 64;
    const int wcol = (w & 1) * 64;
    const int fr = lane & 15;
    const int fq = lane >> 4;          // 0..3
    int aoff[4][2], boff[4][2];
#pragma unroll
    for (int i = 0; i < 4; ++i)
#pragma unroll
        for (int s = 0; s < 2; ++s) {
            int kc = s * 4 + fq;
            int slot = kc ^ (fr & 7);
            aoff[i][s] = (wrow + i * 16 + fr) * BK + slot * 8;
            boff[i][s] = (wcol + i * 16 + fr) * BK + slot * 8;
        }

    floatx4 acc[4][4];
#pragma unroll
    for (int mi = 0; mi < 4; ++mi)
#pragma unroll
        for (int ni = 0; ni < 4; ++ni) acc[mi][ni] = (floatx4){0.f, 0.f, 0.f, 0.f};

    for (int k0 = 0; k0 < K_DIM; k0 += BK) {
        __syncthreads();  // prev iteration's LDS reads done before overwrite
#pragma unroll
        for (int i = 0; i < 4; ++i) {
            __builtin_amdgcn_global_load_lds((const AS1 void*)(gA[i] + k0),
                                             (AS3 void*)lA[i], 16, 0, 0);
            __builtin_amdgcn_global_load_lds((const AS1 void*)(gB[i] + k0),
                                             (AS3 void*)lB[i], 16, 0, 0);
        }
        __syncthreads();  // vmcnt drained before barrier

#pragma unroll
        for (int s = 0; s < 2; ++s) {
            bf16x8 af[4], bf[4];
#pragma unroll
            for (int i = 0; i < 4; ++i) {
                af[i] = *(const bf16x8*)&sA[aoff[i][s]];
                bf[i] = *(const bf16x8*)&sB[boff[i][s]];
            }
#pragma unroll
            for (int mi = 0; mi < 4; ++mi)
#pragma unroll
                for (int ni = 0; ni < 4; ++ni)
                    acc[mi][ni] = __builtin_amdgcn_mfma_f32_16x16x32_bf16(
                        af[mi], bf[ni], acc[mi][ni], 0, 0, 0);
        }
    }

    // Epilogue. 16x16 C/D: col = lane&15, row = (lane>>4)*4 + reg  [m89/m91]
    const int crow = tile_m + wrow + fq * 4;
    const int ccol = tile_n + wcol + fr;
#pragma unroll
    for (int mi = 0; mi < 4; ++mi)
#pragma unroll
        for (int ni = 0; ni < 4; ++ni)
#pragma unroll
            for (int r = 0; r < 4; ++r) {
                int gm = crow + mi * 16 + r;
                int gn = ccol + ni * 16;
                C[(size_t)gm * N_DIM + gn] = acc[mi][ni][r] + bmean;
            }
}

// ---------------------------------------------------------------------------
extern "C" void kernel_launch(void* const* d_in, const int* in_sizes, int n_in,
                              void* d_out, int out_size, void* d_ws, size_t ws_size,
                              hipStream_t stream) {
    (void)in_sizes; (void)n_in; (void)out_size;
    const float* x   = (const float*)d_in[0];  // [16,512,2048]
    const float* Adj = (const float*)d_in[1];  // [2048,2048]
    const float* W   = (const float*)d_in[2];  // [64,2048]
    const float* b   = (const float*)d_in[3];  // [64]
    float* out = (float*)d_out;                // [16,512,2048] fp32

    // ws: wbar @0 (8 KB) | bmean @8192 | weff bf16 @16384 (8.39 MB) | xbf
    char* ws = (char*)d_ws;
    float* wbar  = (float*)ws;
    float* bmean = (float*)(ws + 8192);
    unsigned short* weff = (unsigned short*)(ws + 16384);
    const size_t weff_bytes = (size_t)N_DIM * N_DIM * 2;
    const size_t xbf_off = 16384 + weff_bytes;
    unsigned short* xbf = (unsigned short*)(ws + xbf_off);

    size_t avail = (ws_size > xbf_off) ? (ws_size - xbf_off) : 0;
    long long max_rows = (long long)(avail / ((size_t)K_DIM * 2)) / BM * BM;
    if (max_rows < BM) max_rows = BM;
    if (max_rows > M_DIM) max_rows = M_DIM;

    prep_kernel<<<N_DIM / 256, 256, 0, stream>>>(W, b, wbar, bmean);
    weff_kernel<<<(int)(((size_t)N_DIM * N_DIM / 8) / 256), 256, 0, stream>>>(Adj, wbar, weff);

    for (long long m0 = 0; m0 < M_DIM; m0 += max_rows) {
        long long rows = (M_DIM - m0 < max_rows) ? (M_DIM - m0) : max_rows;
        convx_kernel<<<(int)rows, 256, 0, stream>>>(x + m0 * K_DIM, xbf);
        dim3 grid(N_DIM / BN, (int)(rows / BM));
        gemm_bt_kernel<<<grid, 256, 0, stream>>>(xbf, weff, bmean, out + m0 * (size_t)N_DIM);
    }
}

// Round 5
// 225.927 us; speedup vs baseline: 1.1099x; 1.0033x over previous
//
#include <hip/hip_runtime.h>

// Problem constants (B=16, T=512, N=2048, U=64) — all inputs/outputs FP32.
#define N_DIM 2048
#define U_DIM 64
#define M_DIM 8192   // B*T
#define K_DIM 2048   // = N

typedef __bf16 bf16x8 __attribute__((ext_vector_type(8)));
typedef float  floatx4 __attribute__((ext_vector_type(4)));
typedef unsigned short ushort8 __attribute__((ext_vector_type(8)));

#define AS1 __attribute__((address_space(1)))
#define AS3 __attribute__((address_space(3)))

__device__ __forceinline__ unsigned short f_to_bf16_rne(float f) {
    unsigned int x;
    __builtin_memcpy(&x, &f, 4);
    x += 0x7fffu + ((x >> 16) & 1u);
    return (unsigned short)(x >> 16);
}

// ---------------------------------------------------------------------------
// Kernel 1: wbar[k] = mean_i W[i,k]  (fp32), bmean = mean(b)
// ---------------------------------------------------------------------------
__global__ __launch_bounds__(256) void prep_kernel(
    const float* __restrict__ W, const float* __restrict__ b,
    float* __restrict__ wbar, float* __restrict__ bmean) {
    int k = blockIdx.x * 256 + threadIdx.x;
    float s = 0.f;
#pragma unroll
    for (int i = 0; i < U_DIM; ++i) s += W[i * N_DIM + k];
    wbar[k] = s * (1.f / U_DIM);

    if (blockIdx.x == 0 && threadIdx.x < 64) {
        float v = b[threadIdx.x];
#pragma unroll
        for (int off = 32; off > 0; off >>= 1) v += __shfl_down(v, off);
        if (threadIdx.x == 0) bmean[0] = v * (1.f / U_DIM);
    }
}

// ---------------------------------------------------------------------------
// Kernel 2 (merged): blocks [0, 2048): weff[j,k] = bf16(Adj[j,k]*wbar[k])
//                    blocks [2048, 10240): xbf = bf16(x)   (independent work,
//                    one dispatch instead of two -> one less launch gap)
// ---------------------------------------------------------------------------
__global__ __launch_bounds__(256) void weff_convx_kernel(
    const float* __restrict__ Adj, const float* __restrict__ wbar,
    unsigned short* __restrict__ weff,
    const float* __restrict__ x, unsigned short* __restrict__ xbf) {
    if (blockIdx.x < 2048) {
        long long idx = ((long long)blockIdx.x * 256 + threadIdx.x) * 8;
        int k = (int)(idx & (N_DIM - 1));
        floatx4 a0 = *(const floatx4*)(Adj + idx);
        floatx4 a1 = *(const floatx4*)(Adj + idx + 4);
        floatx4 w0 = *(const floatx4*)(wbar + k);
        floatx4 w1 = *(const floatx4*)(wbar + k + 4);
        ushort8 ov;
#pragma unroll
        for (int j = 0; j < 4; ++j) {
            ov[j]     = f_to_bf16_rne(a0[j] * w0[j]);
            ov[j + 4] = f_to_bf16_rne(a1[j] * w1[j]);
        }
        *(ushort8*)(weff + idx) = ov;
    } else {
        long long idx = ((long long)(blockIdx.x - 2048) * 256 + threadIdx.x) * 8;
        floatx4 a0 = *(const floatx4*)(x + idx);
        floatx4 a1 = *(const floatx4*)(x + idx + 4);
        ushort8 ov;
#pragma unroll
        for (int j = 0; j < 4; ++j) {
            ov[j]     = f_to_bf16_rne(a0[j]);
            ov[j + 4] = f_to_bf16_rne(a1[j]);
        }
        *(ushort8*)(xbf + idx) = ov;
    }
}

// Fallback converter for chunked path (small ws)
__global__ __launch_bounds__(256) void convx_kernel(
    const float* __restrict__ x, unsigned short* __restrict__ xbf) {
    long long idx = ((long long)blockIdx.x * 256 + threadIdx.x) * 8;
    floatx4 a0 = *(const floatx4*)(x + idx);
    floatx4 a1 = *(const floatx4*)(x + idx + 4);
    ushort8 ov;
#pragma unroll
    for (int j = 0; j < 4; ++j) {
        ov[j]     = f_to_bf16_rne(a0[j]);
        ov[j + 4] = f_to_bf16_rne(a1[j]);
    }
    *(ushort8*)(xbf + idx) = ov;
}

// ---------------------------------------------------------------------------
// Kernel 3: C[m,j] = sum_k A[m,k]*Bt[j,k] + bmean   (bf16 in, fp32 acc/out)
// 128x128 tile, BK=64 (32 K-iters), 4 waves; wave = 64x64 via 4x4 of
// mfma_f32_16x16x32. LDS rows 128 B, XOR swizzle slot = kc ^ (row&7)
// -> 0 bank conflicts (R4 measured). Staging via global_load_lds width=16.
// NEW: 1-D grid + XCD-aware swizzle — xcd (id&7) owns n-tiles {2*xcd,2*xcd+1}
// for ALL m-tiles: per-XCD B working set = 1 MB (L2-resident), consecutive
// local ids share an A-tile (2x A reuse in L2).
// ---------------------------------------------------------------------------
#define BM 128
#define BN 128
#define BK 64

__global__ __launch_bounds__(256) void gemm_bt_kernel(
    const unsigned short* __restrict__ A,    // [M, K] bf16 bits (xbf)
    const unsigned short* __restrict__ Bt,   // [N, K] bf16 bits (weff)
    const float* __restrict__ bmeanp,
    float* __restrict__ C,                   // [M, N] fp32
    int mtiles) {
    __shared__ __align__(16) unsigned short sA[BM * BK];  // 16 KB
    __shared__ __align__(16) unsigned short sB[BN * BK];  // 16 KB

    // XCD swizzle (8 XCDs, round-robin dispatch heuristic)
    const int id    = blockIdx.x;
    const int xcd   = id & 7;
    const int local = id >> 3;
    const int nt    = xcd * 2 + (local & 1);   // 0..15
    const int mt    = local >> 1;              // 0..mtiles-1
    const int tile_m = mt * BM;
    const int tile_n = nt * BN;

    const int tid  = threadIdx.x;
    const int w    = tid >> 6;    // wave 0..3
    const int lane = tid & 63;

    const float bmean = bmeanp[0];

    // staging: chunk = 1024 B = 8 rows of 128 B; wave w stages chunks w*4..w*4+3.
    const int srow_in = lane >> 3;                    // 0..7 row within chunk
    const int skc     = (lane & 7) ^ srow_in;         // swizzled fetch chunk
    const int scol    = skc * 8;
    const unsigned short* gA[4];
    const unsigned short* gB[4];
    unsigned short* lA[4];
    unsigned short* lB[4];
#pragma unroll
    for (int i = 0; i < 4; ++i) {
        int c = w * 4 + i;
        gA[i] = A  + (size_t)(tile_m + c * 8 + srow_in) * K_DIM + scol;
        gB[i] = Bt + (size_t)(tile_n + c * 8 + srow_in) * K_DIM + scol;
        lA[i] = &sA[c * 8 * BK];
        lB[i] = &sB[c * 8 * BK];
    }

    // fragment read offsets. 16x16x32 frag: m(n)=lane&15, k=(lane>>4)*8+j.
    const int wrow = (w >> 1) * 64;
    const int wcol = (w & 1) * 64;
    const int fr = lane & 15;
    const int fq = lane >> 4;          // 0..3
    int aoff[4][2], boff[4][2];
#pragma unroll
    for (int i = 0; i < 4; ++i)
#pragma unroll
        for (int s = 0; s < 2; ++s) {
            int kc = s * 4 + fq;
            int slot = kc ^ (fr & 7);
            aoff[i][s] = (wrow + i * 16 + fr) * BK + slot * 8;
            boff[i][s] = (wcol + i * 16 + fr) * BK + slot * 8;
        }

    floatx4 acc[4][4];
#pragma unroll
    for (int mi = 0; mi < 4; ++mi)
#pragma unroll
        for (int ni = 0; ni < 4; ++ni) acc[mi][ni] = (floatx4){0.f, 0.f, 0.f, 0.f};

    for (int k0 = 0; k0 < K_DIM; k0 += BK) {
        __syncthreads();  // prev iteration's LDS reads done before overwrite
#pragma unroll
        for (int i = 0; i < 4; ++i) {
            __builtin_amdgcn_global_load_lds((const AS1 void*)(gA[i] + k0),
                                             (AS3 void*)lA[i], 16, 0, 0);
            __builtin_amdgcn_global_load_lds((const AS1 void*)(gB[i] + k0),
                                             (AS3 void*)lB[i], 16, 0, 0);
        }
        __syncthreads();  // vmcnt drained before barrier

#pragma unroll
        for (int s = 0; s < 2; ++s) {
            bf16x8 af[4], bf[4];
#pragma unroll
            for (int i = 0; i < 4; ++i) {
                af[i] = *(const bf16x8*)&sA[aoff[i][s]];
                bf[i] = *(const bf16x8*)&sB[boff[i][s]];
            }
#pragma unroll
            for (int mi = 0; mi < 4; ++mi)
#pragma unroll
                for (int ni = 0; ni < 4; ++ni)
                    acc[mi][ni] = __builtin_amdgcn_mfma_f32_16x16x32_bf16(
                        af[mi], bf[ni], acc[mi][ni], 0, 0, 0);
        }
    }

    // Epilogue. 16x16 C/D: col = lane&15, row = (lane>>4)*4 + reg  [m89/m91]
    const int crow = tile_m + wrow + fq * 4;
    const int ccol = tile_n + wcol + fr;
#pragma unroll
    for (int mi = 0; mi < 4; ++mi)
#pragma unroll
        for (int ni = 0; ni < 4; ++ni)
#pragma unroll
            for (int r = 0; r < 4; ++r) {
                int gm = crow + mi * 16 + r;
                int gn = ccol + ni * 16;
                C[(size_t)gm * N_DIM + gn] = acc[mi][ni][r] + bmean;
            }
    (void)mtiles;
}

// ---------------------------------------------------------------------------
extern "C" void kernel_launch(void* const* d_in, const int* in_sizes, int n_in,
                              void* d_out, int out_size, void* d_ws, size_t ws_size,
                              hipStream_t stream) {
    (void)in_sizes; (void)n_in; (void)out_size;
    const float* x   = (const float*)d_in[0];  // [16,512,2048]
    const float* Adj = (const float*)d_in[1];  // [2048,2048]
    const float* W   = (const float*)d_in[2];  // [64,2048]
    const float* b   = (const float*)d_in[3];  // [64]
    float* out = (float*)d_out;                // [16,512,2048] fp32

    // ws: wbar @0 (8 KB) | bmean @8192 | weff bf16 @16384 (8.39 MB) | xbf
    char* ws = (char*)d_ws;
    float* wbar  = (float*)ws;
    float* bmean = (float*)(ws + 8192);
    unsigned short* weff = (unsigned short*)(ws + 16384);
    const size_t weff_bytes = (size_t)N_DIM * N_DIM * 2;
    const size_t xbf_off = 16384 + weff_bytes;
    unsigned short* xbf = (unsigned short*)(ws + xbf_off);

    size_t avail = (ws_size > xbf_off) ? (ws_size - xbf_off) : 0;
    long long max_rows = (long long)(avail / ((size_t)K_DIM * 2)) / BM * BM;
    if (max_rows < BM) max_rows = BM;
    if (max_rows > M_DIM) max_rows = M_DIM;

    prep_kernel<<<N_DIM / 256, 256, 0, stream>>>(W, b, wbar, bmean);

    if (max_rows == M_DIM) {
        // full-size path: merged weff+convx, then one swizzled GEMM
        weff_convx_kernel<<<2048 + M_DIM, 256, 0, stream>>>(Adj, wbar, weff, x, xbf);
        gemm_bt_kernel<<<(N_DIM / BN) * (M_DIM / BM), 256, 0, stream>>>(
            xbf, weff, bmean, out, M_DIM / BM);
    } else {
        weff_convx_kernel<<<2048, 256, 0, stream>>>(Adj, wbar, weff, x, xbf);
        for (long long m0 = 0; m0 < M_DIM; m0 += max_rows) {
            long long rows = (M_DIM - m0 < max_rows) ? (M_DIM - m0) : max_rows;
            convx_kernel<<<(int)rows, 256, 0, stream>>>(x + m0 * K_DIM, xbf);
            gemm_bt_kernel<<<(N_DIM / BN) * (int)(rows / BM), 256, 0, stream>>>(
                xbf, weff, bmean, out + m0 * (size_t)N_DIM, (int)(rows / BM));
        }
    }
}